// Round 14
// baseline (833.677 us; speedup 1.0000x reference)
//
#include <hip/hip_runtime.h>
#include <cstdint>

#define NN 50000
#define NE 800000
#define IN_DIM 16
#define H 32
#define EDGE_DIM 4
#define T_STEPS 4
#define NPB 32
#define NBLK ((NN + NPB - 1) / NPB)   // 1563
#define SBLK 196                      // scan blocks (196*256 >= NN+1)
#define CHUNK 128                     // edges per LDS msg buffer (2 subs of 64)

typedef __bf16 bf16x8 __attribute__((ext_vector_type(8)));
typedef float f32x4 __attribute__((ext_vector_type(4)));
typedef unsigned int u32x4 __attribute__((ext_vector_type(4)));

__device__ __forceinline__ uint32_t bf_rne1(float f) {
    uint32_t u = __float_as_uint(f);
    return (u + 0x7FFFu + ((u >> 16) & 1u)) >> 16;
}
__device__ __forceinline__ float bf2f(uint32_t h16) { return __uint_as_float(h16 << 16); }
__device__ __forceinline__ uint32_t bfpair(float a, float b) {
    return (bf_rne1(b) << 16) | bf_rne1(a);
}
__device__ __forceinline__ bf16x8 asbf(u32x4 u) { return __builtin_bit_cast(bf16x8, u); }
__device__ __forceinline__ f32x4 MFMA(bf16x8 a, bf16x8 b, f32x4 c) {
    return __builtin_amdgcn_mfma_f32_16x16x32_bf16(a, b, c, 0, 0, 0);
}

// packed h row: 32 u32 = 128B. words [0..15] = hi in fragment order
// (pk[4kg..4kg+3] = orig hi words {2kg,2kg+1,8+2kg,8+2kg+1}), [16..31] = lo same order.
// writer thread cq (channels 4cq..4cq+3): u32-pair offset = (cq&3)*4 + (cq>>2)*2.
__device__ __forceinline__ void store_hpk(uint32_t* hpk, int n, int cq, float4 a) {
    int off = (cq & 3) * 4 + (cq >> 2) * 2;
    uint32_t p0 = bfpair(a.x, a.y), p1 = bfpair(a.z, a.w);
    *(uint2*)(hpk + (size_t)n * 32 + off) = make_uint2(p0, p1);
    float r0 = a.x - bf2f(p0 & 0xFFFFu), r1 = a.y - bf2f(p0 >> 16);
    float r2 = a.z - bf2f(p1 & 0xFFFFu), r3 = a.w - bf2f(p1 >> 16);
    *(uint2*)(hpk + (size_t)n * 32 + 16 + off) = make_uint2(bfpair(r0, r1), bfpair(r2, r3));
}

// ---------------- embedding: h0 = inputs @ W_emb (+ packed bf16 hi/lo) ----------------
__global__ __launch_bounds__(256) void embed_kernel(const float* __restrict__ inputs,
                                                    const float* __restrict__ W_emb,
                                                    float* __restrict__ h,
                                                    uint32_t* __restrict__ hpk) {
    int idx = blockIdx.x * 256 + threadIdx.x;
    if (idx >= NN * 8) return;
    int n = idx >> 3, cq = idx & 7;
    const float* xr = inputs + (size_t)n * IN_DIM;
    float4 a = make_float4(0.f, 0.f, 0.f, 0.f);
#pragma unroll
    for (int k = 0; k < IN_DIM; ++k) {
        float xk = xr[k];
        float4 w = *(const float4*)(W_emb + k * 32 + cq * 4);
        a.x = fmaf(xk, w.x, a.x); a.y = fmaf(xk, w.y, a.y);
        a.z = fmaf(xk, w.z, a.z); a.w = fmaf(xk, w.w, a.w);
    }
    *(float4*)(h + (size_t)n * 32 + cq * 4) = a;
    store_hpk(hpk, n, cq, a);
}

// ---------------- CSR build ----------------
__global__ __launch_bounds__(256) void hist_kernel(const int* __restrict__ dst, int* __restrict__ deg) {
    int e = blockIdx.x * 256 + threadIdx.x;
    if (e < NE) atomicAdd(&deg[dst[e]], 1);
}

__global__ __launch_bounds__(256) void scan_part(const int* __restrict__ deg, int* __restrict__ bsum) {
    __shared__ int red[256];
    int i = blockIdx.x * 256 + threadIdx.x;
    red[threadIdx.x] = (i < NN) ? deg[i] : 0;
    __syncthreads();
    for (int off = 128; off > 0; off >>= 1) {
        if (threadIdx.x < off) red[threadIdx.x] += red[threadIdx.x + off];
        __syncthreads();
    }
    if (threadIdx.x == 0) bsum[blockIdx.x] = red[0];
}

__global__ __launch_bounds__(256) void scan_tops(const int* __restrict__ bsum, int* __restrict__ btop) {
    __shared__ int s[256];
    int tid = threadIdx.x;
    int v0 = (tid < SBLK) ? bsum[tid] : 0;
    s[tid] = v0;
    __syncthreads();
    for (int off = 1; off < 256; off <<= 1) {
        int v = (tid >= off) ? s[tid - off] : 0;
        __syncthreads();
        s[tid] += v;
        __syncthreads();
    }
    if (tid < SBLK) btop[tid] = s[tid] - v0;   // exclusive
}

__global__ __launch_bounds__(256) void scan_final(const int* __restrict__ deg,
                                                  const int* __restrict__ btop,
                                                  int* __restrict__ row_ptr) {
    __shared__ int s[256];
    int tid = threadIdx.x;
    int i = blockIdx.x * 256 + tid;
    int v0 = (i < NN) ? deg[i] : 0;
    s[tid] = v0;
    __syncthreads();
    for (int off = 1; off < 256; off <<= 1) {
        int v = (tid >= off) ? s[tid - off] : 0;
        __syncthreads();
        s[tid] += v;
        __syncthreads();
    }
    if (i <= NN) row_ptr[i] = btop[blockIdx.x] + s[tid] - v0;
}

__global__ __launch_bounds__(256) void scatter_kernel(const int* __restrict__ src, const int* __restrict__ dst,
                                                      const int* __restrict__ row_ptr, int* __restrict__ cnt,
                                                      uint2* __restrict__ se_sorted) {
    int e = blockIdx.x * 256 + threadIdx.x;
    if (e >= NE) return;
    int d = dst[e];
    int pos = row_ptr[d] + atomicAdd(&cnt[d], 1);
    se_sorted[pos] = make_uint2((unsigned)src[e], (unsigned)e);
}

// ---------------- ef re-layout: packed {hi0,hi1,lo0,lo1} per (t,p) ----------------
__global__ __launch_bounds__(256) void ef_sort_kernel(const float* __restrict__ e_feats,
                                                      const uint2* __restrict__ se_sorted,
                                                      u32x4* __restrict__ ef4) {
    int p = blockIdx.x * 256 + threadIdx.x;
    if (p >= NE) return;
    int e = (int)se_sorted[p].y;
    float buf[16];
    const float4* srcp = (const float4*)(e_feats + (size_t)e * (EDGE_DIM * T_STEPS));
#pragma unroll
    for (int q = 0; q < 4; ++q) {
        float4 v = srcp[q];
        buf[4 * q + 0] = v.x; buf[4 * q + 1] = v.y; buf[4 * q + 2] = v.z; buf[4 * q + 3] = v.w;
    }
#pragma unroll
    for (int t = 0; t < T_STEPS; ++t) {
        float f0 = buf[t], f1 = buf[4 + t], f2 = buf[8 + t], f3 = buf[12 + t];
        uint32_t h0 = bfpair(f0, f1), h1 = bfpair(f2, f3);
        float r0 = f0 - bf2f(h0 & 0xFFFFu), r1 = f1 - bf2f(h0 >> 16);
        float r2 = f2 - bf2f(h1 & 0xFFFFu), r3 = f3 - bf2f(h1 >> 16);
        u32x4 o = {h0, h1, bfpair(r0, r1), bfpair(r2, r3)};
        ef4[(size_t)t * NE + p] = o;
    }
}

// ---------------- We -> B-fragment prep (r7-verified layout) ----------------
__global__ __launch_bounds__(256) void wefrag_kernel(const float* __restrict__ We_in,
                                                     const float* __restrict__ We_out,
                                                     u32x4* __restrict__ frag) {
    int idx = blockIdx.x * 256 + threadIdx.x;
    if (idx >= 3 * 2 * 2 * 2 * 64) return;
    int lane = idx & 63;
    int hl = (idx >> 6) & 1;
    int nt = (idx >> 7) & 1;
    int ks = (idx >> 8) & 1;
    int mat = idx >> 9;
    const float* W = (mat < 2) ? (We_in + (size_t)mat * 36 * 32) : We_out;
    int col = (lane & 15) + nt * 16;
    int kb = ks * 32 + ((lane >> 4) & 3) * 4;
    u32x4 o;
#pragma unroll
    for (int i = 0; i < 4; ++i) {
        int k0 = kb + (i >= 2 ? 16 : 0) + (i & 1) * 2;
        float v0 = (k0 < 36) ? W[(size_t)k0 * 32 + col] : 0.f;
        float v1 = (k0 + 1 < 36) ? W[(size_t)(k0 + 1) * 32 + col] : 0.f;
        if (hl) {
            v0 -= bf2f(bf_rne1(v0));
            v1 -= bf2f(bf_rne1(v1));
        }
        o[i] = bfpair(v0, v1);
    }
    frag[idx] = o;
}

// ---------------- fused layer: depth-4 pipelined MFMA edge GEMM + segsum + node update ----------------
__global__ __launch_bounds__(256) void layer_kernel(const float* __restrict__ h,
                                                    const uint32_t* __restrict__ hpk,
                                                    const u32x4* __restrict__ ef4,
                                                    const uint2* __restrict__ se,
                                                    const int* __restrict__ row_ptr,
                                                    const float* __restrict__ rain0,
                                                    const u32x4* __restrict__ wfrag,
                                                    const float* __restrict__ Wn,
                                                    const float* __restrict__ Wrain,
                                                    float* __restrict__ hnew,
                                                    uint32_t* __restrict__ hnpk,
                                                    float* __restrict__ out,
                                                    int t, int last) {
    __shared__ float msg[CHUNK * 36];   // [edge-in-chunk][ch], pad 36
    __shared__ float shl[NPB * 33];
    __shared__ float sagg[NPB * 33];
    __shared__ float srain[NPB];
    __shared__ int srp[NPB + 1];

    int tid = threadIdx.x;
    int nb0 = blockIdx.x * NPB;
    int nEnd = min(nb0 + NPB, NN);
    int nloc = nEnd - nb0;

    if (tid <= nloc) srp[tid] = row_ptr[nb0 + tid];
    for (int i = tid; i < nloc * 32; i += 256) {
        int g = i >> 5, c = i & 31;
        shl[g * 33 + c] = h[(size_t)(nb0 + g) * 32 + c];
    }
    if (tid < NPB) srain[tid] = 0.f;
    __syncthreads();
    int e0 = srp[0], e1 = srp[nloc];

    int lane = tid & 63, w = tid >> 6;
    int l15 = lane & 15, kg = lane >> 4;

    // hoist B fragments into registers
    u32x4 b[2][2][2];
#pragma unroll
    for (int ks = 0; ks < 2; ++ks)
#pragma unroll
        for (int nt = 0; nt < 2; ++nt)
#pragma unroll
            for (int hl = 0; hl < 2; ++hl)
                b[ks][nt][hl] = wfrag[((ks * 2 + nt) * 2 + hl) * 64 + lane];

    // segsum ownership: thread (sg, sl) -> node sg, channels sl*4..+3
    int sg = tid >> 3, sl = tid & 7;
    int arb = (sg < nloc) ? srp[sg] : 0;
    int are = (sg < nloc) ? srp[sg + 1] : 0;
    float4 aggv = make_float4(0.f, 0.f, 0.f, 0.f);

    struct Frag { u32x4 ah, al, e4; };

    auto loadS = [&](int gs) -> int {
        int p = e0 + gs * 64 + w * 16 + l15;
        int pc = p < e1 ? p : e1 - 1;
        return (int)se[pc].x;
    };
    auto loadFrag = [&](int s, int gs) -> Frag {
        Frag f;
        const u32x4* hp = (const u32x4*)(hpk + (size_t)s * 32);
        f.ah = hp[kg];
        f.al = hp[4 + kg];
        if (kg == 0) {
            int p = e0 + gs * 64 + w * 16 + l15;
            int pc = p < e1 ? p : e1 - 1;
            f.e4 = ef4[pc];
        } else {
            f.e4 = u32x4{0u, 0u, 0u, 0u};
        }
        return f;
    };
    auto compute = [&](Frag f, int rowbase) {
        u32x4 a1h = {f.e4[0], f.e4[1], 0u, 0u};
        u32x4 a1l = {f.e4[2], f.e4[3], 0u, 0u};
        f32x4 c0 = {0.f, 0.f, 0.f, 0.f};
        f32x4 c1 = {0.f, 0.f, 0.f, 0.f};
        bf16x8 Ah = asbf(f.ah), Al = asbf(f.al), Eh = asbf(a1h), El = asbf(a1l);
        c0 = MFMA(Ah, asbf(b[0][0][0]), c0);
        c0 = MFMA(Ah, asbf(b[0][0][1]), c0);
        c0 = MFMA(Al, asbf(b[0][0][0]), c0);
        c0 = MFMA(Eh, asbf(b[1][0][0]), c0);
        c0 = MFMA(Eh, asbf(b[1][0][1]), c0);
        c0 = MFMA(El, asbf(b[1][0][0]), c0);
        c1 = MFMA(Ah, asbf(b[0][1][0]), c1);
        c1 = MFMA(Ah, asbf(b[0][1][1]), c1);
        c1 = MFMA(Al, asbf(b[0][1][0]), c1);
        c1 = MFMA(Eh, asbf(b[1][1][0]), c1);
        c1 = MFMA(Eh, asbf(b[1][1][1]), c1);
        c1 = MFMA(El, asbf(b[1][1][0]), c1);
        // C/D: col(channel) = lane&15, row(edge) = kg*4 + reg  [r7-verified end-to-end]
        int rb = rowbase + kg * 4;
#pragma unroll
        for (int r = 0; r < 4; ++r) {
            msg[(rb + r) * 36 + l15] = fmaxf(c0[r], 0.f);
            msg[(rb + r) * 36 + 16 + l15] = fmaxf(c1[r], 0.f);
        }
    };
    auto segsum = [&](int c) {
        int cb = e0 + c * CHUNK;
        if (sg < nloc) {
            int lo = max(arb, cb), hi2 = min(are, cb + CHUNK);
            for (int p2 = lo; p2 < hi2; ++p2) {
                float4 v = *(const float4*)&msg[(p2 - cb) * 36 + sl * 4];
                aggv.x += v.x; aggv.y += v.y; aggv.z += v.z; aggv.w += v.w;
            }
        }
    };

    if (e0 < e1) {
        int nch = (e1 - e0 + CHUNK - 1) / CHUNK;
        // bootstrap depth-4 ring: frags for subs 0..3, se for subs 4..7
        int s0 = loadS(0), s1 = loadS(1), s2 = loadS(2), s3 = loadS(3);
        Frag f0 = loadFrag(s0, 0);
        Frag f1 = loadFrag(s1, 1);
        Frag f2 = loadFrag(s2, 2);
        Frag f3 = loadFrag(s3, 3);
        s0 = loadS(4); s1 = loadS(5); s2 = loadS(6); s3 = loadS(7);

#define SUB_BODY(I, FS, SS)                                 \
        {                                                   \
            Frag fN = loadFrag(SS, (I) + 4);                \
            int sN = loadS((I) + 8);                        \
            compute(FS, ((I) & 1) * 64 + w * 16);           \
            FS = fN; SS = sN;                               \
        }

        int cc = 0;
#pragma unroll 1
        for (; cc + 1 < nch; cc += 2) {
            int i0 = cc * 2;
            SUB_BODY(i0 + 0, f0, s0)
            SUB_BODY(i0 + 1, f1, s1)
            __syncthreads();
            segsum(cc);
            __syncthreads();
            SUB_BODY(i0 + 2, f2, s2)
            SUB_BODY(i0 + 3, f3, s3)
            __syncthreads();
            segsum(cc + 1);
            __syncthreads();
        }
        if (cc < nch) {
            int i0 = cc * 2;
            SUB_BODY(i0 + 0, f0, s0)
            SUB_BODY(i0 + 1, f1, s1)
            __syncthreads();
            segsum(cc);
            __syncthreads();
        }
#undef SUB_BODY
    }
    if (sg < nloc) {
        sagg[sg * 33 + sl * 4 + 0] = aggv.x;
        sagg[sg * 33 + sl * 4 + 1] = aggv.y;
        sagg[sg * 33 + sl * 4 + 2] = aggv.z;
        sagg[sg * 33 + sl * 4 + 3] = aggv.w;
    }
    __syncthreads();

    // ---- node phase: thread (nl, cq) -> node nl, channels cq*4..+3 (exclusive) ----
    int nl = tid >> 3, cq = tid & 7;
    if (nl < nloc) {
        int n = nb0 + nl;
        float4 a = make_float4(0.f, 0.f, 0.f, 0.f);
#pragma unroll 8
        for (int k = 0; k < 32; ++k) {
            float xk = shl[nl * 33 + k];
            float4 wv = *(const float4*)(Wn + (size_t)k * 32 + cq * 4);
            a.x = fmaf(xk, wv.x, a.x); a.y = fmaf(xk, wv.y, a.y);
            a.z = fmaf(xk, wv.z, a.z); a.w = fmaf(xk, wv.w, a.w);
        }
#pragma unroll 8
        for (int k = 0; k < 32; ++k) {
            float xk = sagg[nl * 33 + k];
            float4 wv = *(const float4*)(Wn + (size_t)(32 + k) * 32 + cq * 4);
            a.x = fmaf(xk, wv.x, a.x); a.y = fmaf(xk, wv.y, a.y);
            a.z = fmaf(xk, wv.z, a.z); a.w = fmaf(xk, wv.w, a.w);
        }
        {
            float rain = rain0[(size_t)n * T_STEPS + t];
            float4 wv = *(const float4*)(Wn + (size_t)64 * 32 + cq * 4);
            a.x = fmaf(rain, wv.x, a.x); a.y = fmaf(rain, wv.y, a.y);
            a.z = fmaf(rain, wv.z, a.z); a.w = fmaf(rain, wv.w, a.w);
        }
        a.x = fmaxf(a.x, 0.f); a.y = fmaxf(a.y, 0.f);
        a.z = fmaxf(a.z, 0.f); a.w = fmaxf(a.w, 0.f);
        *(float4*)(hnew + (size_t)n * 32 + cq * 4) = a;
        store_hpk(hnpk, n, cq, a);
        if (last) {
            float4 wr = *(const float4*)(Wrain + cq * 4);
            float rv = a.x * wr.x + a.y * wr.y + a.z * wr.z + a.w * wr.w;
            atomicAdd(&srain[nl], rv);
        }
    }
    if (last) {
        __syncthreads();
        if (tid < nloc) out[(size_t)(nb0 + tid) * T_STEPS + t] = srain[tid];
    }
}

extern "C" void kernel_launch(void* const* d_in, const int* in_sizes, int n_in,
                              void* d_out, int out_size, void* d_ws, size_t ws_size,
                              hipStream_t stream) {
    const float* inputs     = (const float*)d_in[0];
    const float* e_feats    = (const float*)d_in[1];
    const float* rain0      = (const float*)d_in[2];
    const float* W_emb      = (const float*)d_in[3];
    const float* W_edge_in  = (const float*)d_in[4];
    const float* W_node_in  = (const float*)d_in[5];
    const float* W_edge_out = (const float*)d_in[6];
    const float* W_node_out = (const float*)d_in[7];
    const float* W_rain     = (const float*)d_in[8];
    const int*   src        = (const int*)d_in[9];
    const int*   dst        = (const int*)d_in[10];
    float* out = (float*)d_out;

    // workspace layout (~84 MB)
    float* h_a = (float*)d_ws;                                   // NN*32
    float* h_b = h_a + (size_t)NN * 32;                          // NN*32
    uint32_t* hpk_a = (uint32_t*)(h_b + (size_t)NN * 32);        // NN*32 u32
    uint32_t* hpk_b = hpk_a + (size_t)NN * 32;                   // NN*32 u32
    u32x4* ef4      = (u32x4*)(hpk_b + (size_t)NN * 32);         // T*NE u32x4
    u32x4* wfrag    = ef4 + (size_t)T_STEPS * NE;                // 1536
    int* row_ptr    = (int*)(wfrag + 1536);                      // NN+1
    int* deg        = row_ptr + (NN + 1);                        // NN
    int* cnt        = deg + NN;                                  // NN
    uint2* se       = (uint2*)(cnt + NN + 1);                    // NE (8B aligned)
    int* bsum       = (int*)(se + NE);                           // SBLK
    int* btop       = bsum + SBLK;                               // SBLK

    embed_kernel<<<(NN * 8 + 255) / 256, 256, 0, stream>>>(inputs, W_emb, h_a, hpk_a);

    // CSR build (hierarchical scan)
    hipMemsetAsync(deg, 0, (size_t)2 * NN * sizeof(int), stream);  // deg + cnt contiguous
    hist_kernel<<<(NE + 255) / 256, 256, 0, stream>>>(dst, deg);
    scan_part<<<SBLK, 256, 0, stream>>>(deg, bsum);
    scan_tops<<<1, 256, 0, stream>>>(bsum, btop);
    scan_final<<<SBLK, 256, 0, stream>>>(deg, btop, row_ptr);
    scatter_kernel<<<(NE + 255) / 256, 256, 0, stream>>>(src, dst, row_ptr, cnt, se);
    ef_sort_kernel<<<(NE + 255) / 256, 256, 0, stream>>>(e_feats, se, ef4);
    wefrag_kernel<<<6, 256, 0, stream>>>(W_edge_in, W_edge_out, wfrag);

    float* hc = h_a;  float* hn = h_b;
    uint32_t* pkc = hpk_a; uint32_t* pkn = hpk_b;
    for (int t = 0; t < T_STEPS; ++t) {
        const u32x4* ef4_t = ef4 + (size_t)t * NE;
        for (int s = 0; s < 3; ++s) {
            int mat = (s < 2) ? s : 2;
            const float* Wn = (s < 2) ? (W_node_in + (size_t)s * 65 * 32) : W_node_out;
            layer_kernel<<<NBLK, 256, 0, stream>>>(hc, pkc, ef4_t, se, row_ptr, rain0,
                                                   wfrag + (size_t)mat * 512, Wn, W_rain,
                                                   hn, pkn, out, t, (s == 2) ? 1 : 0);
            float* tf = hc; hc = hn; hn = tf;
            uint32_t* tp = pkc; pkc = pkn; pkn = tp;
        }
    }
}

// Round 15
// 633.181 us; speedup vs baseline: 1.3166x; 1.3166x over previous
//
#include <hip/hip_runtime.h>
#include <cstdint>

#define NN 50000
#define NE 800000
#define IN_DIM 16
#define H 32
#define EDGE_DIM 4
#define T_STEPS 4
#define NPB 32
#define NBLK ((NN + NPB - 1) / NPB)   // 1563
#define SBLK 196                      // scan blocks (196*256 >= NN+1)

typedef __bf16 bf16x8 __attribute__((ext_vector_type(8)));
typedef float f32x4 __attribute__((ext_vector_type(4)));
typedef unsigned int u32x4 __attribute__((ext_vector_type(4)));

__device__ __forceinline__ uint32_t bf_rne1(float f) {
    uint32_t u = __float_as_uint(f);
    return (u + 0x7FFFu + ((u >> 16) & 1u)) >> 16;
}
__device__ __forceinline__ float bf2f(uint32_t h16) { return __uint_as_float(h16 << 16); }
__device__ __forceinline__ uint32_t bfpair(float a, float b) {
    return (bf_rne1(b) << 16) | bf_rne1(a);
}
__device__ __forceinline__ bf16x8 asbf(u32x4 u) { return __builtin_bit_cast(bf16x8, u); }
__device__ __forceinline__ f32x4 MFMA(bf16x8 a, bf16x8 b, f32x4 c) {
    return __builtin_amdgcn_mfma_f32_16x16x32_bf16(a, b, c, 0, 0, 0);
}

// packed h row: 32 u32 = 128B. words [0..15] = hi in fragment order
// (pk[4kg..4kg+3] = orig hi words {2kg,2kg+1,8+2kg,8+2kg+1}), [16..31] = lo same order.
__device__ __forceinline__ void store_hpk(uint32_t* hpk, int n, int cq, float4 a) {
    int off = (cq & 3) * 4 + (cq >> 2) * 2;
    uint32_t p0 = bfpair(a.x, a.y), p1 = bfpair(a.z, a.w);
    *(uint2*)(hpk + (size_t)n * 32 + off) = make_uint2(p0, p1);
    float r0 = a.x - bf2f(p0 & 0xFFFFu), r1 = a.y - bf2f(p0 >> 16);
    float r2 = a.z - bf2f(p1 & 0xFFFFu), r3 = a.w - bf2f(p1 >> 16);
    *(uint2*)(hpk + (size_t)n * 32 + 16 + off) = make_uint2(bfpair(r0, r1), bfpair(r2, r3));
}

// ---------------- embedding ----------------
__global__ __launch_bounds__(256) void embed_kernel(const float* __restrict__ inputs,
                                                    const float* __restrict__ W_emb,
                                                    float* __restrict__ h,
                                                    uint32_t* __restrict__ hpk) {
    int idx = blockIdx.x * 256 + threadIdx.x;
    if (idx >= NN * 8) return;
    int n = idx >> 3, cq = idx & 7;
    const float* xr = inputs + (size_t)n * IN_DIM;
    float4 a = make_float4(0.f, 0.f, 0.f, 0.f);
#pragma unroll
    for (int k = 0; k < IN_DIM; ++k) {
        float xk = xr[k];
        float4 w = *(const float4*)(W_emb + k * 32 + cq * 4);
        a.x = fmaf(xk, w.x, a.x); a.y = fmaf(xk, w.y, a.y);
        a.z = fmaf(xk, w.z, a.z); a.w = fmaf(xk, w.w, a.w);
    }
    *(float4*)(h + (size_t)n * 32 + cq * 4) = a;
    store_hpk(hpk, n, cq, a);
}

// ---------------- CSR build ----------------
__global__ __launch_bounds__(256) void hist_kernel(const int* __restrict__ dst, int* __restrict__ deg) {
    int e = blockIdx.x * 256 + threadIdx.x;
    if (e < NE) atomicAdd(&deg[dst[e]], 1);
}

__global__ __launch_bounds__(256) void scan_part(const int* __restrict__ deg, int* __restrict__ bsum) {
    __shared__ int red[256];
    int i = blockIdx.x * 256 + threadIdx.x;
    red[threadIdx.x] = (i < NN) ? deg[i] : 0;
    __syncthreads();
    for (int off = 128; off > 0; off >>= 1) {
        if (threadIdx.x < off) red[threadIdx.x] += red[threadIdx.x + off];
        __syncthreads();
    }
    if (threadIdx.x == 0) bsum[blockIdx.x] = red[0];
}

__global__ __launch_bounds__(256) void scan_tops(const int* __restrict__ bsum, int* __restrict__ btop) {
    __shared__ int s[256];
    int tid = threadIdx.x;
    int v0 = (tid < SBLK) ? bsum[tid] : 0;
    s[tid] = v0;
    __syncthreads();
    for (int off = 1; off < 256; off <<= 1) {
        int v = (tid >= off) ? s[tid - off] : 0;
        __syncthreads();
        s[tid] += v;
        __syncthreads();
    }
    if (tid < SBLK) btop[tid] = s[tid] - v0;   // exclusive
}

__global__ __launch_bounds__(256) void scan_final(const int* __restrict__ deg,
                                                  const int* __restrict__ btop,
                                                  int* __restrict__ row_ptr) {
    __shared__ int s[256];
    int tid = threadIdx.x;
    int i = blockIdx.x * 256 + tid;
    int v0 = (i < NN) ? deg[i] : 0;
    s[tid] = v0;
    __syncthreads();
    for (int off = 1; off < 256; off <<= 1) {
        int v = (tid >= off) ? s[tid - off] : 0;
        __syncthreads();
        s[tid] += v;
        __syncthreads();
    }
    if (i <= NN) row_ptr[i] = btop[blockIdx.x] + s[tid] - v0;
}

__global__ __launch_bounds__(256) void scatter_kernel(const int* __restrict__ src, const int* __restrict__ dst,
                                                      const int* __restrict__ row_ptr, int* __restrict__ cnt,
                                                      uint2* __restrict__ se_sorted) {
    int e = blockIdx.x * 256 + threadIdx.x;
    if (e >= NE) return;
    int d = dst[e];
    int pos = row_ptr[d] + atomicAdd(&cnt[d], 1);
    se_sorted[pos] = make_uint2((unsigned)src[e], (unsigned)e);
}

// ---------------- ef re-layout: packed {hi0,hi1,lo0,lo1} per (t,p) ----------------
__global__ __launch_bounds__(256) void ef_sort_kernel(const float* __restrict__ e_feats,
                                                      const uint2* __restrict__ se_sorted,
                                                      u32x4* __restrict__ ef4) {
    int p = blockIdx.x * 256 + threadIdx.x;
    if (p >= NE) return;
    int e = (int)se_sorted[p].y;
    float buf[16];
    const float4* srcp = (const float4*)(e_feats + (size_t)e * (EDGE_DIM * T_STEPS));
#pragma unroll
    for (int q = 0; q < 4; ++q) {
        float4 v = srcp[q];
        buf[4 * q + 0] = v.x; buf[4 * q + 1] = v.y; buf[4 * q + 2] = v.z; buf[4 * q + 3] = v.w;
    }
#pragma unroll
    for (int t = 0; t < T_STEPS; ++t) {
        float f0 = buf[t], f1 = buf[4 + t], f2 = buf[8 + t], f3 = buf[12 + t];
        uint32_t h0 = bfpair(f0, f1), h1 = bfpair(f2, f3);
        float r0 = f0 - bf2f(h0 & 0xFFFFu), r1 = f1 - bf2f(h0 >> 16);
        float r2 = f2 - bf2f(h1 & 0xFFFFu), r3 = f3 - bf2f(h1 >> 16);
        u32x4 o = {h0, h1, bfpair(r0, r1), bfpair(r2, r3)};
        ef4[(size_t)t * NE + p] = o;
    }
}

// ---------------- We -> B-fragment prep (r7-verified layout) ----------------
__global__ __launch_bounds__(256) void wefrag_kernel(const float* __restrict__ We_in,
                                                     const float* __restrict__ We_out,
                                                     u32x4* __restrict__ frag) {
    int idx = blockIdx.x * 256 + threadIdx.x;
    if (idx >= 3 * 2 * 2 * 2 * 64) return;
    int lane = idx & 63;
    int hl = (idx >> 6) & 1;
    int nt = (idx >> 7) & 1;
    int ks = (idx >> 8) & 1;
    int mat = idx >> 9;
    const float* W = (mat < 2) ? (We_in + (size_t)mat * 36 * 32) : We_out;
    int col = (lane & 15) + nt * 16;
    int kb = ks * 32 + ((lane >> 4) & 3) * 4;
    u32x4 o;
#pragma unroll
    for (int i = 0; i < 4; ++i) {
        int k0 = kb + (i >= 2 ? 16 : 0) + (i & 1) * 2;
        float v0 = (k0 < 36) ? W[(size_t)k0 * 32 + col] : 0.f;
        float v1 = (k0 + 1 < 36) ? W[(size_t)(k0 + 1) * 32 + col] : 0.f;
        if (hl) {
            v0 -= bf2f(bf_rne1(v0));
            v1 -= bf2f(bf_rne1(v1));
        }
        o[i] = bfpair(v0, v1);
    }
    frag[idx] = o;
}

// ---------------- fused layer: BARRIER-FREE wave-local edge GEMM + segsum + node update ----
// Wave w owns nodes nb0+w*8 .. +7 and exactly their CSR edge range. Messages live in a
// per-wave double-buffered LDS tile (same-wave ds ordering via lgkmcnt; no __syncthreads
// anywhere -> no vmcnt(0) pipeline drains; waves slip freely for latency hiding).
__global__ __launch_bounds__(256) void layer_kernel(const float* __restrict__ h,
                                                    const uint32_t* __restrict__ hpk,
                                                    const u32x4* __restrict__ ef4,
                                                    const uint2* __restrict__ se,
                                                    const int* __restrict__ row_ptr,
                                                    const float* __restrict__ rain0,
                                                    const u32x4* __restrict__ wfrag,
                                                    const float* __restrict__ Wn,
                                                    const float* __restrict__ Wrain,
                                                    float* __restrict__ hnew,
                                                    uint32_t* __restrict__ hnpk,
                                                    float* __restrict__ out,
                                                    int t, int last) {
    __shared__ float msg[4][2][16 * 36];   // [wave][parity][edge][ch(pad 36)]
    __shared__ float shl[NPB * 36];        // own nodes' h (wave-local quadrants)
    __shared__ float sagg[NPB * 36];       // aggregated messages

    int tid = threadIdx.x;
    int lane = tid & 63, w = tid >> 6;
    int nb0 = blockIdx.x * NPB;
    int l15 = lane & 15, kg = lane >> 4;

    // wave-local CSR pointers via shuffle (lanes 0..8 meaningful)
    int rpv = row_ptr[min(nb0 + w * 8 + min(lane, 8), NN)];
    int e0w = __shfl(rpv, 0);
    int e1w = __shfl(rpv, 8);
    int sg = lane >> 3, sl = lane & 7;     // segsum/node owner: node sg, channels sl*4..+3
    int arb = __shfl(rpv, sg);
    int are = __shfl(rpv, sg + 1);

    // stage own 8 nodes' h rows (wave-local; 1 float4 per lane)
    {
        int nl = w * 8 + sg;
        int n = nb0 + nl;
        if (n < NN)
            *(float4*)&shl[nl * 36 + sl * 4] = *(const float4*)(h + (size_t)n * 32 + sl * 4);
    }

    // hoist B fragments into registers
    u32x4 b[2][2][2];
#pragma unroll
    for (int ks = 0; ks < 2; ++ks)
#pragma unroll
        for (int nt = 0; nt < 2; ++nt)
#pragma unroll
            for (int hl = 0; hl < 2; ++hl)
                b[ks][nt][hl] = wfrag[((ks * 2 + nt) * 2 + hl) * 64 + lane];

    float4 aggv = make_float4(0.f, 0.f, 0.f, 0.f);
    float* msgW0 = &msg[w][0][0];
    float* msgW1 = &msg[w][1][0];

    struct Frag { u32x4 ah, al, e4; };

    auto loadFrag = [&](int i) -> Frag {
        Frag f;
        int p = e0w + i * 16 + l15;
        int pc = p < e1w ? p : e1w - 1;
        int s = (int)se[pc].x;
        const u32x4* hp = (const u32x4*)(hpk + (size_t)s * 32);
        f.ah = hp[kg];
        f.al = hp[4 + kg];
        f.e4 = (kg == 0) ? ef4[pc] : u32x4{0u, 0u, 0u, 0u};
        return f;
    };
    auto compute = [&](Frag f, float* msgW) {
        u32x4 a1h = {f.e4[0], f.e4[1], 0u, 0u};
        u32x4 a1l = {f.e4[2], f.e4[3], 0u, 0u};
        f32x4 c0 = {0.f, 0.f, 0.f, 0.f};
        f32x4 c1 = {0.f, 0.f, 0.f, 0.f};
        bf16x8 Ah = asbf(f.ah), Al = asbf(f.al), Eh = asbf(a1h), El = asbf(a1l);
        c0 = MFMA(Ah, asbf(b[0][0][0]), c0);
        c0 = MFMA(Ah, asbf(b[0][0][1]), c0);
        c0 = MFMA(Al, asbf(b[0][0][0]), c0);
        c0 = MFMA(Eh, asbf(b[1][0][0]), c0);
        c0 = MFMA(Eh, asbf(b[1][0][1]), c0);
        c0 = MFMA(El, asbf(b[1][0][0]), c0);
        c1 = MFMA(Ah, asbf(b[0][1][0]), c1);
        c1 = MFMA(Ah, asbf(b[0][1][1]), c1);
        c1 = MFMA(Al, asbf(b[0][1][0]), c1);
        c1 = MFMA(Eh, asbf(b[1][1][0]), c1);
        c1 = MFMA(Eh, asbf(b[1][1][1]), c1);
        c1 = MFMA(El, asbf(b[1][1][0]), c1);
        // C/D: col(channel)=lane&15, row(edge)=kg*4+reg  [r7-verified end-to-end]
#pragma unroll
        for (int r = 0; r < 4; ++r) {
            msgW[(kg * 4 + r) * 36 + l15] = fmaxf(c0[r], 0.f);
            msgW[(kg * 4 + r) * 36 + 16 + l15] = fmaxf(c1[r], 0.f);
        }
    };
    auto segsum = [&](int i, const float* msgW) {
        int tb = e0w + i * 16;
        int lo = max(arb, tb), hi2 = min(are, tb + 16);
        for (int p2 = lo; p2 < hi2; ++p2) {
            float4 v = *(const float4*)&msgW[(p2 - tb) * 36 + sl * 4];
            aggv.x += v.x; aggv.y += v.y; aggv.z += v.z; aggv.w += v.w;
        }
    };

    if (e1w > e0w) {
        int nT = (e1w - e0w + 15) >> 4;
        Frag f0 = loadFrag(0);
        Frag f1 = loadFrag(1);
#pragma unroll 1
        for (int i = 0; i < nT; ++i) {
            Frag fn = loadFrag(i + 2);
            float* mw = (i & 1) ? msgW1 : msgW0;
            compute(f0, mw);
            segsum(i, mw);          // same-wave LDS RAW: compiler inserts lgkmcnt
            f0 = f1; f1 = fn;
        }
    }
    {
        int nl = w * 8 + sg;
        *(float4*)&sagg[nl * 36 + sl * 4] = aggv;
    }

    // ---- node phase (wave-local): lane -> node sg, channels sl*4..+3 ----
    int nl = w * 8 + sg;
    int n = nb0 + nl;
    if (n < NN) {
        float4 a = make_float4(0.f, 0.f, 0.f, 0.f);
#pragma unroll 8
        for (int k = 0; k < 32; ++k) {
            float xk = shl[nl * 36 + k];
            float4 wv = *(const float4*)(Wn + (size_t)k * 32 + sl * 4);
            a.x = fmaf(xk, wv.x, a.x); a.y = fmaf(xk, wv.y, a.y);
            a.z = fmaf(xk, wv.z, a.z); a.w = fmaf(xk, wv.w, a.w);
        }
#pragma unroll 8
        for (int k = 0; k < 32; ++k) {
            float xk = sagg[nl * 36 + k];
            float4 wv = *(const float4*)(Wn + (size_t)(32 + k) * 32 + sl * 4);
            a.x = fmaf(xk, wv.x, a.x); a.y = fmaf(xk, wv.y, a.y);
            a.z = fmaf(xk, wv.z, a.z); a.w = fmaf(xk, wv.w, a.w);
        }
        {
            float rain = rain0[(size_t)n * T_STEPS + t];
            float4 wv = *(const float4*)(Wn + (size_t)64 * 32 + sl * 4);
            a.x = fmaf(rain, wv.x, a.x); a.y = fmaf(rain, wv.y, a.y);
            a.z = fmaf(rain, wv.z, a.z); a.w = fmaf(rain, wv.w, a.w);
        }
        a.x = fmaxf(a.x, 0.f); a.y = fmaxf(a.y, 0.f);
        a.z = fmaxf(a.z, 0.f); a.w = fmaxf(a.w, 0.f);
        *(float4*)(hnew + (size_t)n * 32 + sl * 4) = a;
        store_hpk(hnpk, n, sl, a);
        if (last) {
            float4 wr = *(const float4*)(Wrain + sl * 4);
            float rv = a.x * wr.x + a.y * wr.y + a.z * wr.z + a.w * wr.w;
            rv += __shfl_xor(rv, 1);
            rv += __shfl_xor(rv, 2);
            rv += __shfl_xor(rv, 4);
            if (sl == 0) out[(size_t)n * T_STEPS + t] = rv;
        }
    }
}

extern "C" void kernel_launch(void* const* d_in, const int* in_sizes, int n_in,
                              void* d_out, int out_size, void* d_ws, size_t ws_size,
                              hipStream_t stream) {
    const float* inputs     = (const float*)d_in[0];
    const float* e_feats    = (const float*)d_in[1];
    const float* rain0      = (const float*)d_in[2];
    const float* W_emb      = (const float*)d_in[3];
    const float* W_edge_in  = (const float*)d_in[4];
    const float* W_node_in  = (const float*)d_in[5];
    const float* W_edge_out = (const float*)d_in[6];
    const float* W_node_out = (const float*)d_in[7];
    const float* W_rain     = (const float*)d_in[8];
    const int*   src        = (const int*)d_in[9];
    const int*   dst        = (const int*)d_in[10];
    float* out = (float*)d_out;

    // workspace layout (~84 MB)
    float* h_a = (float*)d_ws;                                   // NN*32
    float* h_b = h_a + (size_t)NN * 32;                          // NN*32
    uint32_t* hpk_a = (uint32_t*)(h_b + (size_t)NN * 32);        // NN*32 u32
    uint32_t* hpk_b = hpk_a + (size_t)NN * 32;                   // NN*32 u32
    u32x4* ef4      = (u32x4*)(hpk_b + (size_t)NN * 32);         // T*NE u32x4
    u32x4* wfrag    = ef4 + (size_t)T_STEPS * NE;                // 1536
    int* row_ptr    = (int*)(wfrag + 1536);                      // NN+1
    int* deg        = row_ptr + (NN + 1);                        // NN
    int* cnt        = deg + NN;                                  // NN
    uint2* se       = (uint2*)(cnt + NN + 1);                    // NE (8B aligned)
    int* bsum       = (int*)(se + NE);                           // SBLK
    int* btop       = bsum + SBLK;                               // SBLK

    embed_kernel<<<(NN * 8 + 255) / 256, 256, 0, stream>>>(inputs, W_emb, h_a, hpk_a);

    // CSR build (hierarchical scan)
    hipMemsetAsync(deg, 0, (size_t)2 * NN * sizeof(int), stream);  // deg + cnt contiguous
    hist_kernel<<<(NE + 255) / 256, 256, 0, stream>>>(dst, deg);
    scan_part<<<SBLK, 256, 0, stream>>>(deg, bsum);
    scan_tops<<<1, 256, 0, stream>>>(bsum, btop);
    scan_final<<<SBLK, 256, 0, stream>>>(deg, btop, row_ptr);
    scatter_kernel<<<(NE + 255) / 256, 256, 0, stream>>>(src, dst, row_ptr, cnt, se);
    ef_sort_kernel<<<(NE + 255) / 256, 256, 0, stream>>>(e_feats, se, ef4);
    wefrag_kernel<<<6, 256, 0, stream>>>(W_edge_in, W_edge_out, wfrag);

    float* hc = h_a;  float* hn = h_b;
    uint32_t* pkc = hpk_a; uint32_t* pkn = hpk_b;
    for (int t = 0; t < T_STEPS; ++t) {
        const u32x4* ef4_t = ef4 + (size_t)t * NE;
        for (int s = 0; s < 3; ++s) {
            int mat = (s < 2) ? s : 2;
            const float* Wn = (s < 2) ? (W_node_in + (size_t)s * 65 * 32) : W_node_out;
            layer_kernel<<<NBLK, 256, 0, stream>>>(hc, pkc, ef4_t, se, row_ptr, rain0,
                                                   wfrag + (size_t)mat * 512, Wn, W_rain,
                                                   hn, pkn, out, t, (s == 2) ? 1 : 0);
            float* tf = hc; hc = hn; hn = tf;
            uint32_t* tp = pkc; pkc = pkn; pkn = tp;
        }
    }
}